// Round 9
// baseline (321.922 us; speedup 1.0000x reference)
//
#include <hip/hip_runtime.h>
#include <cstddef>
#include <cstdint>

#define THREADS 256

typedef short bf16x8 __attribute__((ext_vector_type(8)));
typedef float f32x4 __attribute__((ext_vector_type(4)));
typedef unsigned short u16x8 __attribute__((ext_vector_type(8)));

#define GLOBAL_AS __attribute__((address_space(1)))
#define LDS_AS    __attribute__((address_space(3)))

// Async global->LDS DMA, 16B per lane (dest must be linear in lane order).
__device__ __forceinline__ void async_copy16(const void* g, void* l) {
    __builtin_amdgcn_global_load_lds((const GLOBAL_AS void*)g, (LDS_AS void*)l, 16, 0, 0);
}

// f32 -> bf16 round-to-nearest-even
__device__ __forceinline__ ushort f2bf(float f) {
    uint32_t u = __float_as_uint(f);
    u = u + 0x7FFFu + ((u >> 16) & 1u);
    return (ushort)(u >> 16);
}
__device__ __forceinline__ float bf2f(ushort h) {
    return __uint_as_float(((uint32_t)h) << 16);
}

// ---------------------------------------------------------------------------
// f32 vector micro-GEMM pieces (used only by wpow for the 128x128 W powers)
// ---------------------------------------------------------------------------
__device__ __forceinline__ void rowfma(float4& acc, const float4 xv,
                                       const float4 w0, const float4 w1,
                                       const float4 w2, const float4 w3) {
    acc.x = fmaf(xv.x, w0.x, acc.x); acc.y = fmaf(xv.x, w0.y, acc.y);
    acc.z = fmaf(xv.x, w0.z, acc.z); acc.w = fmaf(xv.x, w0.w, acc.w);
    acc.x = fmaf(xv.y, w1.x, acc.x); acc.y = fmaf(xv.y, w1.y, acc.y);
    acc.z = fmaf(xv.y, w1.z, acc.z); acc.w = fmaf(xv.y, w1.w, acc.w);
    acc.x = fmaf(xv.z, w2.x, acc.x); acc.y = fmaf(xv.z, w2.y, acc.y);
    acc.z = fmaf(xv.z, w2.z, acc.z); acc.w = fmaf(xv.z, w2.w, acc.w);
    acc.x = fmaf(xv.w, w3.x, acc.x); acc.y = fmaf(xv.w, w3.y, acc.y);
    acc.z = fmaf(xv.w, w3.z, acc.z); acc.w = fmaf(xv.w, w3.w, acc.w);
}

__device__ __forceinline__ void mm32(const float4* Ws4, const float4* Xs4,
                                     int c4, int rb,
                                     float4& a0, float4& a1, float4& a2, float4& a3) {
#pragma unroll 4
    for (int kq = 0; kq < 32; ++kq) {
        float4 w0 = Ws4[(4 * kq + 0) * 32 + c4];
        float4 w1 = Ws4[(4 * kq + 1) * 32 + c4];
        float4 w2 = Ws4[(4 * kq + 2) * 32 + c4];
        float4 w3 = Ws4[(4 * kq + 3) * 32 + c4];
        float4 x0 = Xs4[(rb + 0) * 32 + kq];
        float4 x1 = Xs4[(rb + 1) * 32 + kq];
        float4 x2 = Xs4[(rb + 2) * 32 + kq];
        float4 x3 = Xs4[(rb + 3) * 32 + kq];
        rowfma(a0, x0, w0, w1, w2, w3);
        rowfma(a1, x1, w0, w1, w2, w3);
        rowfma(a2, x2, w0, w1, w2, w3);
        rowfma(a3, x3, w0, w1, w2, w3);
    }
}

// ---------------------------------------------------------------------------
// wpow: blocks 0-3 -> -W^2 slices; blocks 4-7 -> W^3 slices. Output stored
// TRANSPOSED (Wt[col][k]), hi/lo-split bf16, XOR-swizzled:
// u16 idx = col*128 + (k ^ ((col&7)<<3)).
// ---------------------------------------------------------------------------
__global__ __launch_bounds__(256, 2)
void wpow_kernel(const float* __restrict__ W,
                 ushort* __restrict__ w3t_hi, ushort* __restrict__ w3t_lo,
                 ushort* __restrict__ nw2t_hi, ushort* __restrict__ nw2t_lo) {
    __shared__ float4 Ws4[128 * 32];  // 64KB: full W
    __shared__ float4 Xs4[32 * 32];   // 16KB: 32-row operand slice
    const int tid = threadIdx.x;
    const int row0 = (blockIdx.x & 3) * 32;
    const bool is3 = blockIdx.x >= 4;
    const float4* __restrict__ W4 = (const float4*)W;

#pragma unroll
    for (int i = 0; i < 16; ++i) Ws4[tid + i * 256] = W4[tid + i * 256];
#pragma unroll
    for (int i = 0; i < 4; ++i) {
        int li = tid + i * 256;
        Xs4[li] = W4[(size_t)(row0 + (li >> 5)) * 32 + (li & 31)];
    }
    __syncthreads();

    const int c4 = tid & 31;
    const int rb = (tid >> 5) * 4;
    float4 a0 = {0.f, 0.f, 0.f, 0.f};
    float4 a1 = {0.f, 0.f, 0.f, 0.f};
    float4 a2 = {0.f, 0.f, 0.f, 0.f};
    float4 a3 = {0.f, 0.f, 0.f, 0.f};
    mm32(Ws4, Xs4, c4, rb, a0, a1, a2, a3);

    if (is3) {  // second multiply: S2 = S1 @ W
        __syncthreads();
        Xs4[(rb + 0) * 32 + c4] = a0;
        Xs4[(rb + 1) * 32 + c4] = a1;
        Xs4[(rb + 2) * 32 + c4] = a2;
        Xs4[(rb + 3) * 32 + c4] = a3;
        __syncthreads();
        a0 = {0.f, 0.f, 0.f, 0.f};
        a1 = {0.f, 0.f, 0.f, 0.f};
        a2 = {0.f, 0.f, 0.f, 0.f};
        a3 = {0.f, 0.f, 0.f, 0.f};
        mm32(Ws4, Xs4, c4, rb, a0, a1, a2, a3);
    }

    ushort* __restrict__ dh = is3 ? w3t_hi : nw2t_hi;
    ushort* __restrict__ dl = is3 ? w3t_lo : nw2t_lo;
    const float sgn = is3 ? 1.0f : -1.0f;
    const int r = row0 + rb;
#pragma unroll
    for (int i = 0; i < 4; ++i) {
        float4 a = (i == 0) ? a0 : (i == 1) ? a1 : (i == 2) ? a2 : a3;
        const int k = r + i;  // k-index (row of W^p)
#pragma unroll
        for (int e = 0; e < 4; ++e) {
            float v = ((e == 0) ? a.x : (e == 1) ? a.y : (e == 2) ? a.z : a.w) * sgn;
            int c = c4 * 4 + e;
            int idx = c * 128 + (k ^ ((c & 7) << 3));
            ushort h = f2bf(v);
            dh[idx] = h;
            dl[idx] = f2bf(v - bf2f(h));
        }
    }
}

// ---------------------------------------------------------------------------
// Dual GEMM via bf16 hi/lo-split MFMA: out = A1 @ B1 + A2 @ B2 (Bt tables
// hold W3 and -W2, transposed/split/swizzled). R6-verified structure.
// ---------------------------------------------------------------------------
__global__ __launch_bounds__(256, 2)
void gemm_dual_mfma(const float* __restrict__ A1, const ushort* __restrict__ B1h,
                    const ushort* __restrict__ B1l,
                    const float* __restrict__ A2, const ushort* __restrict__ B2h,
                    const ushort* __restrict__ B2l,
                    float* __restrict__ out, int N) {
    __shared__ ushort WtHi[16384];  // 32KB  Wt[col][k] hi, swizzled
    __shared__ ushort WtLo[16384];  // 32KB
    __shared__ ushort XsHi[4096];   // 8KB   Xs[row][k] hi, swizzled
    __shared__ ushort XsLo[4096];   // 8KB
    const int tid = threadIdx.x;
    const int row0 = blockIdx.x * 32;
    const int l = tid & 63, w = tid >> 6;
    const int mt = w & 1, ntb = (w >> 1) * 4;
    const int fr = l & 15, fh = l >> 4;

    f32x4 acc[4];
#pragma unroll
    for (int nt = 0; nt < 4; ++nt) acc[nt] = (f32x4){0.f, 0.f, 0.f, 0.f};

    for (int pass = 0; pass < 2; ++pass) {
        const float* __restrict__ Asrc = pass ? A2 : A1;
        const ushort* __restrict__ Bh = pass ? B2h : B1h;
        const ushort* __restrict__ Bl = pass ? B2l : B1l;
        if (pass) __syncthreads();  // pass-0 readers done before restage

#pragma unroll
        for (int i = 0; i < 8; ++i) {
            async_copy16(Bh + tid * 8 + i * 2048, WtHi + tid * 8 + i * 2048);
            async_copy16(Bl + tid * 8 + i * 2048, WtLo + tid * 8 + i * 2048);
        }

        // stage Xs: thread -> (row = tid>>3, 16 k's at (tid&7)*16); convert+split
        {
            const int row = tid >> 3, kb = (tid & 7) * 16;
            int gr = row0 + row;
            if (gr >= N) gr = N - 1;  // clamped rows never stored
            const float4* __restrict__ ap =
                (const float4*)(Asrc + (size_t)gr * 128) + (kb >> 2);
            float4 v0 = ap[0], v1 = ap[1], v2 = ap[2], v3 = ap[3];
            float f[16] = {v0.x, v0.y, v0.z, v0.w, v1.x, v1.y, v1.z, v1.w,
                           v2.x, v2.y, v2.z, v2.w, v3.x, v3.y, v3.z, v3.w};
            ushort hi[16], lo[16];
#pragma unroll
            for (int i = 0; i < 16; ++i) {
                hi[i] = f2bf(f[i]);
                lo[i] = f2bf(f[i] - bf2f(hi[i]));
            }
#pragma unroll
            for (int g = 0; g < 2; ++g) {
                int idx = row * 128 + ((kb + 8 * g) ^ ((row & 7) << 3));
                bf16x8 vh, vl;
#pragma unroll
                for (int j = 0; j < 8; ++j) {
                    vh[j] = (short)hi[8 * g + j];
                    vl[j] = (short)lo[8 * g + j];
                }
                *(bf16x8*)&XsHi[idx] = vh;
                *(bf16x8*)&XsLo[idx] = vl;
            }
        }
        __syncthreads();  // drains async vmcnt + ds writes

#pragma unroll
        for (int ks = 0; ks < 4; ++ks) {
            const int arow = mt * 16 + fr;
            const int aoff = arow * 128 + ((ks * 32 + fh * 8) ^ ((arow & 7) << 3));
            bf16x8 ah = *(const bf16x8*)&XsHi[aoff];
            bf16x8 al = *(const bf16x8*)&XsLo[aoff];
#pragma unroll
            for (int nt = 0; nt < 4; ++nt) {
                const int brow = (ntb + nt) * 16 + fr;
                const int boff = brow * 128 + ((ks * 32 + fh * 8) ^ ((brow & 7) << 3));
                bf16x8 bh = *(const bf16x8*)&WtHi[boff];
                bf16x8 bl = *(const bf16x8*)&WtLo[boff];
                acc[nt] = __builtin_amdgcn_mfma_f32_16x16x32_bf16(ah, bh, acc[nt], 0, 0, 0);
                acc[nt] = __builtin_amdgcn_mfma_f32_16x16x32_bf16(al, bh, acc[nt], 0, 0, 0);
                acc[nt] = __builtin_amdgcn_mfma_f32_16x16x32_bf16(ah, bl, acc[nt], 0, 0, 0);
            }
        }
    }

    // epilogue: verified C/D map: col = lane&15, row = (lane>>4)*4 + reg
#pragma unroll
    for (int nt = 0; nt < 4; ++nt) {
        const int col = (ntb + nt) * 16 + fr;
#pragma unroll
        for (int i = 0; i < 4; ++i) {
            const int rr = row0 + mt * 16 + fh * 4 + i;
            if (rr < N) out[(size_t)rr * 128 + col] = acc[nt][i];
        }
    }
}

// ---------------------------------------------------------------------------
// Fused convert + histogram: blocks [0,cb) convert X f32 -> bf16; blocks
// [cb, cb+eb) histogram edge rows.
// ---------------------------------------------------------------------------
__global__ void hist_conv_kernel(const int* __restrict__ erows, int* __restrict__ counts,
                                 int E, const float* __restrict__ X,
                                 ushort* __restrict__ Xbf, int ngroups, int cb) {
    const int b = blockIdx.x;
    if (b < cb) {
        int i = b * 256 + threadIdx.x;  // one u16x8 group (8 elems)
        if (i < ngroups) {
            const float4* __restrict__ X4 = (const float4*)X;
            float4 v0 = X4[i * 2 + 0];
            float4 v1 = X4[i * 2 + 1];
            u16x8 o;
            o[0] = f2bf(v0.x); o[1] = f2bf(v0.y); o[2] = f2bf(v0.z); o[3] = f2bf(v0.w);
            o[4] = f2bf(v1.x); o[5] = f2bf(v1.y); o[6] = f2bf(v1.z); o[7] = f2bf(v1.w);
            ((u16x8*)Xbf)[i] = o;
        }
    } else {
        int e = (b - cb) * 256 + threadIdx.x;
        if (e < E) atomicAdd(&counts[erows[e]], 1);
    }
}

__global__ __launch_bounds__(1024)
void scanA_kernel(const int* __restrict__ counts, int* __restrict__ rowptr,
                  int* __restrict__ blocksum, int n) {
    __shared__ int buf[1024];
    const int tid = threadIdx.x;
    const int i = blockIdx.x * 1024 + tid;
    int v = (i < n) ? counts[i] : 0;
    buf[tid] = v;
    __syncthreads();
#pragma unroll
    for (int off = 1; off < 1024; off <<= 1) {
        int t = (tid >= off) ? buf[tid - off] : 0;
        __syncthreads();
        buf[tid] += t;
        __syncthreads();
    }
    if (i < n) rowptr[i + 1] = buf[tid];
    if (tid == 1023) blocksum[blockIdx.x] = buf[1023];
}

// Also emits bucket cursors: bcur[b] = rowptr[32*b] (buckets of 32 rows).
__global__ void scanBC_kernel(int* __restrict__ rowptr, int* __restrict__ cursor,
                              int* __restrict__ bcur, const int* __restrict__ blocksum,
                              int n, int nb) {
    __shared__ int off[64];
    const int tid = threadIdx.x;
    if (tid < 64) {
        int v = (tid < nb) ? blocksum[tid] : 0;
        int orig = v;
#pragma unroll
        for (int o = 1; o < 64; o <<= 1) {
            int t = __shfl_up(v, o);
            if (tid >= o) v += t;
        }
        off[tid] = v - orig;  // exclusive prefix
    }
    __syncthreads();
    int i = blockIdx.x * blockDim.x + tid;
    if (i < n) {
        int v = rowptr[i + 1] + off[i >> 10];
        rowptr[i + 1] = v;
        cursor[i + 1] = v;
        if (((i + 1) & 31) == 0) bcur[(i + 1) >> 5] = v;
    }
    if (i == 0) { rowptr[0] = 0; cursor[0] = 0; bcur[0] = 0; }
}

// Pass 1: bucket edges (32 rows/bucket) -> bucketed[pos] = edge id.
// Active write frontier ~= NB lines (L2-resident), lines fill densely.
__global__ void bucket_scatter_kernel(const int* __restrict__ erows,
                                      int* __restrict__ bcur,
                                      int* __restrict__ bucketed, int E) {
    int e = blockIdx.x * blockDim.x + threadIdx.x;
    if (e < E) {
        int b = erows[e] >> 5;
        int pos = atomicAdd(&bcur[b], 1);
        bucketed[pos] = e;
    }
}

// Pass 2: bucket-ordered slots -> final CSR. Writes for one bucket land in
// its contiguous ~4KB csr region, processed by temporally-adjacent blocks.
__global__ void csr_fill_kernel(const int* __restrict__ bucketed,
                                const int* __restrict__ erows,
                                const int* __restrict__ ecols,
                                const float* __restrict__ evals,
                                int* __restrict__ cursor, int2* __restrict__ csr, int E) {
    int i = blockIdx.x * blockDim.x + threadIdx.x;
    if (i < E) {
        int e = bucketed[i];
        int r = erows[e];
        int pos = atomicAdd(&cursor[r], 1);
        int2 p;
        p.x = ecols[e];
        p.y = __float_as_int(2.0f * evals[e]);
        csr[pos] = p;
    }
}

// ---------------------------------------------------------------------------
// Gather SpMM over bf16 source: S[row] = sum_e 2*val_e * src[col_e]
// (- init[row] if init). 32 lanes/row, 4 cols/lane (ushort4 = 8B loads),
// 8-edge unrolled, dual accumulators. Output f32 or bf16 (WRITE_BF).
// ---------------------------------------------------------------------------
__device__ __forceinline__ float4 bf4f(ushort4 v) {
    float4 r;
    r.x = bf2f(v.x); r.y = bf2f(v.y); r.z = bf2f(v.z); r.w = bf2f(v.w);
    return r;
}

template <bool WRITE_BF>
__global__ __launch_bounds__(256, 8)
void spmm_gather_bf(const int* __restrict__ rowptr, const int2* __restrict__ csr,
                    const ushort* __restrict__ src, const float* __restrict__ init,
                    void* __restrict__ dst, int N) {
    long long idx = (long long)blockIdx.x * blockDim.x + threadIdx.x;
    int row = (int)(idx >> 5);
    if (row >= N) return;
    int lane = (int)(idx & 31);
    const ushort4* __restrict__ S4 = (const ushort4*)src;  // [col*32 + lane]
    float4 accA = {0.f, 0.f, 0.f, 0.f};
    float4 accB = {0.f, 0.f, 0.f, 0.f};
    if (init) {
        float4 t = ((const float4*)init)[(size_t)row * 32 + lane];
        accA.x = -t.x; accA.y = -t.y; accA.z = -t.z; accA.w = -t.w;
    }
    int p = rowptr[row];
    const int p1 = rowptr[row + 1];
    for (; p + 7 < p1; p += 8) {
        int2 cv0 = csr[p + 0];
        int2 cv1 = csr[p + 1];
        int2 cv2 = csr[p + 2];
        int2 cv3 = csr[p + 3];
        int2 cv4 = csr[p + 4];
        int2 cv5 = csr[p + 5];
        int2 cv6 = csr[p + 6];
        int2 cv7 = csr[p + 7];
        float4 x0 = bf4f(S4[(size_t)cv0.x * 32 + lane]);
        float4 x1 = bf4f(S4[(size_t)cv1.x * 32 + lane]);
        float4 x2 = bf4f(S4[(size_t)cv2.x * 32 + lane]);
        float4 x3 = bf4f(S4[(size_t)cv3.x * 32 + lane]);
        float4 x4 = bf4f(S4[(size_t)cv4.x * 32 + lane]);
        float4 x5 = bf4f(S4[(size_t)cv5.x * 32 + lane]);
        float4 x6 = bf4f(S4[(size_t)cv6.x * 32 + lane]);
        float4 x7 = bf4f(S4[(size_t)cv7.x * 32 + lane]);
        float v0 = __int_as_float(cv0.y);
        float v1 = __int_as_float(cv1.y);
        float v2 = __int_as_float(cv2.y);
        float v3 = __int_as_float(cv3.y);
        float v4 = __int_as_float(cv4.y);
        float v5 = __int_as_float(cv5.y);
        float v6 = __int_as_float(cv6.y);
        float v7 = __int_as_float(cv7.y);
        accA.x = fmaf(v0, x0.x, accA.x); accA.y = fmaf(v0, x0.y, accA.y);
        accA.z = fmaf(v0, x0.z, accA.z); accA.w = fmaf(v0, x0.w, accA.w);
        accB.x = fmaf(v1, x1.x, accB.x); accB.y = fmaf(v1, x1.y, accB.y);
        accB.z = fmaf(v1, x1.z, accB.z); accB.w = fmaf(v1, x1.w, accB.w);
        accA.x = fmaf(v2, x2.x, accA.x); accA.y = fmaf(v2, x2.y, accA.y);
        accA.z = fmaf(v2, x2.z, accA.z); accA.w = fmaf(v2, x2.w, accA.w);
        accB.x = fmaf(v3, x3.x, accB.x); accB.y = fmaf(v3, x3.y, accB.y);
        accB.z = fmaf(v3, x3.z, accB.z); accB.w = fmaf(v3, x3.w, accB.w);
        accA.x = fmaf(v4, x4.x, accA.x); accA.y = fmaf(v4, x4.y, accA.y);
        accA.z = fmaf(v4, x4.z, accA.z); accA.w = fmaf(v4, x4.w, accA.w);
        accB.x = fmaf(v5, x5.x, accB.x); accB.y = fmaf(v5, x5.y, accB.y);
        accB.z = fmaf(v5, x5.z, accB.z); accB.w = fmaf(v5, x5.w, accB.w);
        accA.x = fmaf(v6, x6.x, accA.x); accA.y = fmaf(v6, x6.y, accA.y);
        accA.z = fmaf(v6, x6.z, accA.z); accA.w = fmaf(v6, x6.w, accA.w);
        accB.x = fmaf(v7, x7.x, accB.x); accB.y = fmaf(v7, x7.y, accB.y);
        accB.z = fmaf(v7, x7.z, accB.z); accB.w = fmaf(v7, x7.w, accB.w);
    }
    for (; p + 3 < p1; p += 4) {
        int2 cv0 = csr[p + 0];
        int2 cv1 = csr[p + 1];
        int2 cv2 = csr[p + 2];
        int2 cv3 = csr[p + 3];
        float4 x0 = bf4f(S4[(size_t)cv0.x * 32 + lane]);
        float4 x1 = bf4f(S4[(size_t)cv1.x * 32 + lane]);
        float4 x2 = bf4f(S4[(size_t)cv2.x * 32 + lane]);
        float4 x3 = bf4f(S4[(size_t)cv3.x * 32 + lane]);
        float v0 = __int_as_float(cv0.y);
        float v1 = __int_as_float(cv1.y);
        float v2 = __int_as_float(cv2.y);
        float v3 = __int_as_float(cv3.y);
        accA.x = fmaf(v0, x0.x, accA.x); accA.y = fmaf(v0, x0.y, accA.y);
        accA.z = fmaf(v0, x0.z, accA.z); accA.w = fmaf(v0, x0.w, accA.w);
        accB.x = fmaf(v1, x1.x, accB.x); accB.y = fmaf(v1, x1.y, accB.y);
        accB.z = fmaf(v1, x1.z, accB.z); accB.w = fmaf(v1, x1.w, accB.w);
        accA.x = fmaf(v2, x2.x, accA.x); accA.y = fmaf(v2, x2.y, accA.y);
        accA.z = fmaf(v2, x2.z, accA.z); accA.w = fmaf(v2, x2.w, accA.w);
        accB.x = fmaf(v3, x3.x, accB.x); accB.y = fmaf(v3, x3.y, accB.y);
        accB.z = fmaf(v3, x3.z, accB.z); accB.w = fmaf(v3, x3.w, accB.w);
    }
    for (; p < p1; ++p) {
        int2 cv = csr[p];
        float v = __int_as_float(cv.y);
        float4 x = bf4f(S4[(size_t)cv.x * 32 + lane]);
        accA.x = fmaf(v, x.x, accA.x);
        accA.y = fmaf(v, x.y, accA.y);
        accA.z = fmaf(v, x.z, accA.z);
        accA.w = fmaf(v, x.w, accA.w);
    }
    float4 acc;
    acc.x = accA.x + accB.x;
    acc.y = accA.y + accB.y;
    acc.z = accA.z + accB.z;
    acc.w = accA.w + accB.w;
    if (WRITE_BF) {
        ushort4 o;
        o.x = f2bf(acc.x); o.y = f2bf(acc.y); o.z = f2bf(acc.z); o.w = f2bf(acc.w);
        ((ushort4*)dst)[(size_t)row * 32 + lane] = o;
    } else {
        ((float4*)dst)[(size_t)row * 32 + lane] = acc;
    }
}

extern "C" void kernel_launch(void* const* d_in, const int* in_sizes, int n_in,
                              void* d_out, int out_size, void* d_ws, size_t ws_size,
                              hipStream_t stream) {
    const float* X     = (const float*)d_in[0];
    const int*   erows = (const int*)d_in[1];
    const int*   ecols = (const int*)d_in[2];
    const float* evals = (const float*)d_in[3];
    const float* W     = (const float*)d_in[4];
    float* out = (float*)d_out;

    const int N = in_sizes[0] / 128;  // 50000
    const int E = in_sizes[1];        // 800000

    // Workspace layout (bases kept 16B-aligned)
    ushort* t2bf    = (ushort*)d_ws;                    // N*128 u16 (12.8MB)
    float*  u2      = (float*)(t2bf + (size_t)N * 128); // N*128 f32
    ushort* xbf     = (ushort*)(u2 + (size_t)N * 128);  // N*128 u16
    ushort* wtab    = xbf + (size_t)N * 128;            // 65536 u16
    ushort* w3t_hi  = wtab;
    ushort* w3t_lo  = wtab + 16384;
    ushort* nw2t_hi = wtab + 32768;
    ushort* nw2t_lo = wtab + 49152;
    int2*   csr     = (int2*)(wtab + 65536);            // E int2
    int*    rowptr  = (int*)(csr + E);                  // N+1
    int*    cursor  = rowptr + (N + 1);                 // N+1
    int*    counts  = cursor + (N + 1);                 // N
    int*    bsum    = counts + N;                       // <=64
    int*    bucketed= bsum + 64;                        // E
    int*    bcur    = bucketed + E;                     // NB+1

    const int e_blocks = (E + 255) / 256;
    const int ngroups  = N * 16;                        // u16x8 groups (N*128/8)
    const int cb       = (ngroups + 255) / 256;         // convert blocks
    const int nb       = (N + 1023) / 1024;
    const int g_blocks = (int)(((long long)N * 32 + 255) / 256);
    const int d_blocks = (N + 31) / 32;

    // --- W powers -> transposed/split/swizzled bf16 tables ---
    wpow_kernel<<<8, THREADS, 0, stream>>>(W, w3t_hi, w3t_lo, nw2t_hi, nw2t_lo);

    // --- CSR build (two-level bucket scatter) + X->bf16 conversion ---
    hipMemsetAsync(counts, 0, (size_t)N * sizeof(int), stream);
    hist_conv_kernel<<<cb + e_blocks, THREADS, 0, stream>>>(erows, counts, E, X, xbf,
                                                            ngroups, cb);
    scanA_kernel<<<nb, 1024, 0, stream>>>(counts, rowptr, bsum, N);
    scanBC_kernel<<<(N + 255) / 256, THREADS, 0, stream>>>(rowptr, cursor, bcur, bsum, N, nb);
    bucket_scatter_kernel<<<e_blocks, THREADS, 0, stream>>>(erows, bcur, bucketed, E);
    csr_fill_kernel<<<e_blocks, THREADS, 0, stream>>>(bucketed, erows, ecols, evals,
                                                      cursor, csr, E);

    // --- Chebyshev chain (reassociated) ---
    // t2bf = bf16(2A.Xbf - X)
    spmm_gather_bf<true><<<g_blocks, THREADS, 0, stream>>>(rowptr, csr, xbf, X, t2bf, N);
    // u2 = 2A.t2bf  (f32 out)
    spmm_gather_bf<false><<<g_blocks, THREADS, 0, stream>>>(rowptr, csr, t2bf, nullptr, u2, N);
    // out = u2@W3 - X@W2
    gemm_dual_mfma<<<d_blocks, THREADS, 0, stream>>>(u2, w3t_hi, w3t_lo,
                                                     X, nw2t_hi, nw2t_lo, out, N);
}

// Round 10
// 150.560 us; speedup vs baseline: 2.1382x; 2.1382x over previous
//
#include <hip/hip_runtime.h>
#include <cstddef>
#include <cstdint>

#define THREADS 256
#define KPART 256        // partition blocks
#define MAXNB 1600       // max buckets (N<=51200); N=50000 -> NB=1563

typedef short bf16x8 __attribute__((ext_vector_type(8)));
typedef float f32x4 __attribute__((ext_vector_type(4)));
typedef unsigned short u16x8 __attribute__((ext_vector_type(8)));

#define GLOBAL_AS __attribute__((address_space(1)))
#define LDS_AS    __attribute__((address_space(3)))

__device__ __forceinline__ void async_copy16(const void* g, void* l) {
    __builtin_amdgcn_global_load_lds((const GLOBAL_AS void*)g, (LDS_AS void*)l, 16, 0, 0);
}

__device__ __forceinline__ ushort f2bf(float f) {
    uint32_t u = __float_as_uint(f);
    u = u + 0x7FFFu + ((u >> 16) & 1u);
    return (ushort)(u >> 16);
}
__device__ __forceinline__ float bf2f(ushort h) {
    return __uint_as_float(((uint32_t)h) << 16);
}

// ---------------------------------------------------------------------------
// f32 vector micro-GEMM pieces (used only by wpow)
// ---------------------------------------------------------------------------
__device__ __forceinline__ void rowfma(float4& acc, const float4 xv,
                                       const float4 w0, const float4 w1,
                                       const float4 w2, const float4 w3) {
    acc.x = fmaf(xv.x, w0.x, acc.x); acc.y = fmaf(xv.x, w0.y, acc.y);
    acc.z = fmaf(xv.x, w0.z, acc.z); acc.w = fmaf(xv.x, w0.w, acc.w);
    acc.x = fmaf(xv.y, w1.x, acc.x); acc.y = fmaf(xv.y, w1.y, acc.y);
    acc.z = fmaf(xv.y, w1.z, acc.z); acc.w = fmaf(xv.y, w1.w, acc.w);
    acc.x = fmaf(xv.z, w2.x, acc.x); acc.y = fmaf(xv.z, w2.y, acc.y);
    acc.z = fmaf(xv.z, w2.z, acc.z); acc.w = fmaf(xv.z, w2.w, acc.w);
    acc.x = fmaf(xv.w, w3.x, acc.x); acc.y = fmaf(xv.w, w3.y, acc.y);
    acc.z = fmaf(xv.w, w3.z, acc.z); acc.w = fmaf(xv.w, w3.w, acc.w);
}

__device__ __forceinline__ void mm32(const float4* Ws4, const float4* Xs4,
                                     int c4, int rb,
                                     float4& a0, float4& a1, float4& a2, float4& a3) {
#pragma unroll 4
    for (int kq = 0; kq < 32; ++kq) {
        float4 w0 = Ws4[(4 * kq + 0) * 32 + c4];
        float4 w1 = Ws4[(4 * kq + 1) * 32 + c4];
        float4 w2 = Ws4[(4 * kq + 2) * 32 + c4];
        float4 w3 = Ws4[(4 * kq + 3) * 32 + c4];
        float4 x0 = Xs4[(rb + 0) * 32 + kq];
        float4 x1 = Xs4[(rb + 1) * 32 + kq];
        float4 x2 = Xs4[(rb + 2) * 32 + kq];
        float4 x3 = Xs4[(rb + 3) * 32 + kq];
        rowfma(a0, x0, w0, w1, w2, w3);
        rowfma(a1, x1, w0, w1, w2, w3);
        rowfma(a2, x2, w0, w1, w2, w3);
        rowfma(a3, x3, w0, w1, w2, w3);
    }
}

// ---------------------------------------------------------------------------
// wpow: -W^2 and W^3 -> transposed, hi/lo-split, XOR-swizzled bf16 tables.
// ---------------------------------------------------------------------------
__global__ __launch_bounds__(256, 2)
void wpow_kernel(const float* __restrict__ W,
                 ushort* __restrict__ w3t_hi, ushort* __restrict__ w3t_lo,
                 ushort* __restrict__ nw2t_hi, ushort* __restrict__ nw2t_lo) {
    __shared__ float4 Ws4[128 * 32];
    __shared__ float4 Xs4[32 * 32];
    const int tid = threadIdx.x;
    const int row0 = (blockIdx.x & 3) * 32;
    const bool is3 = blockIdx.x >= 4;
    const float4* __restrict__ W4 = (const float4*)W;

#pragma unroll
    for (int i = 0; i < 16; ++i) Ws4[tid + i * 256] = W4[tid + i * 256];
#pragma unroll
    for (int i = 0; i < 4; ++i) {
        int li = tid + i * 256;
        Xs4[li] = W4[(size_t)(row0 + (li >> 5)) * 32 + (li & 31)];
    }
    __syncthreads();

    const int c4 = tid & 31;
    const int rb = (tid >> 5) * 4;
    float4 a0 = {0.f, 0.f, 0.f, 0.f};
    float4 a1 = {0.f, 0.f, 0.f, 0.f};
    float4 a2 = {0.f, 0.f, 0.f, 0.f};
    float4 a3 = {0.f, 0.f, 0.f, 0.f};
    mm32(Ws4, Xs4, c4, rb, a0, a1, a2, a3);

    if (is3) {
        __syncthreads();
        Xs4[(rb + 0) * 32 + c4] = a0;
        Xs4[(rb + 1) * 32 + c4] = a1;
        Xs4[(rb + 2) * 32 + c4] = a2;
        Xs4[(rb + 3) * 32 + c4] = a3;
        __syncthreads();
        a0 = {0.f, 0.f, 0.f, 0.f};
        a1 = {0.f, 0.f, 0.f, 0.f};
        a2 = {0.f, 0.f, 0.f, 0.f};
        a3 = {0.f, 0.f, 0.f, 0.f};
        mm32(Ws4, Xs4, c4, rb, a0, a1, a2, a3);
    }

    ushort* __restrict__ dh = is3 ? w3t_hi : nw2t_hi;
    ushort* __restrict__ dl = is3 ? w3t_lo : nw2t_lo;
    const float sgn = is3 ? 1.0f : -1.0f;
    const int r = row0 + rb;
#pragma unroll
    for (int i = 0; i < 4; ++i) {
        float4 a = (i == 0) ? a0 : (i == 1) ? a1 : (i == 2) ? a2 : a3;
        const int k = r + i;
#pragma unroll
        for (int e = 0; e < 4; ++e) {
            float v = ((e == 0) ? a.x : (e == 1) ? a.y : (e == 2) ? a.z : a.w) * sgn;
            int c = c4 * 4 + e;
            int idx = c * 128 + (k ^ ((c & 7) << 3));
            ushort h = f2bf(v);
            dh[idx] = h;
            dl[idx] = f2bf(v - bf2f(h));
        }
    }
}

// ---------------------------------------------------------------------------
// Dual GEMM via bf16 hi/lo-split MFMA (R6-verified structure).
// ---------------------------------------------------------------------------
__global__ __launch_bounds__(256, 2)
void gemm_dual_mfma(const float* __restrict__ A1, const ushort* __restrict__ B1h,
                    const ushort* __restrict__ B1l,
                    const float* __restrict__ A2, const ushort* __restrict__ B2h,
                    const ushort* __restrict__ B2l,
                    float* __restrict__ out, int N) {
    __shared__ ushort WtHi[16384];
    __shared__ ushort WtLo[16384];
    __shared__ ushort XsHi[4096];
    __shared__ ushort XsLo[4096];
    const int tid = threadIdx.x;
    const int row0 = blockIdx.x * 32;
    const int l = tid & 63, w = tid >> 6;
    const int mt = w & 1, ntb = (w >> 1) * 4;
    const int fr = l & 15, fh = l >> 4;

    f32x4 acc[4];
#pragma unroll
    for (int nt = 0; nt < 4; ++nt) acc[nt] = (f32x4){0.f, 0.f, 0.f, 0.f};

    for (int pass = 0; pass < 2; ++pass) {
        const float* __restrict__ Asrc = pass ? A2 : A1;
        const ushort* __restrict__ Bh = pass ? B2h : B1h;
        const ushort* __restrict__ Bl = pass ? B2l : B1l;
        if (pass) __syncthreads();

#pragma unroll
        for (int i = 0; i < 8; ++i) {
            async_copy16(Bh + tid * 8 + i * 2048, WtHi + tid * 8 + i * 2048);
            async_copy16(Bl + tid * 8 + i * 2048, WtLo + tid * 8 + i * 2048);
        }

        {
            const int row = tid >> 3, kb = (tid & 7) * 16;
            int gr = row0 + row;
            if (gr >= N) gr = N - 1;
            const float4* __restrict__ ap =
                (const float4*)(Asrc + (size_t)gr * 128) + (kb >> 2);
            float4 v0 = ap[0], v1 = ap[1], v2 = ap[2], v3 = ap[3];
            float f[16] = {v0.x, v0.y, v0.z, v0.w, v1.x, v1.y, v1.z, v1.w,
                           v2.x, v2.y, v2.z, v2.w, v3.x, v3.y, v3.z, v3.w};
            ushort hi[16], lo[16];
#pragma unroll
            for (int i = 0; i < 16; ++i) {
                hi[i] = f2bf(f[i]);
                lo[i] = f2bf(f[i] - bf2f(hi[i]));
            }
#pragma unroll
            for (int g = 0; g < 2; ++g) {
                int idx = row * 128 + ((kb + 8 * g) ^ ((row & 7) << 3));
                bf16x8 vh, vl;
#pragma unroll
                for (int j = 0; j < 8; ++j) {
                    vh[j] = (short)hi[8 * g + j];
                    vl[j] = (short)lo[8 * g + j];
                }
                *(bf16x8*)&XsHi[idx] = vh;
                *(bf16x8*)&XsLo[idx] = vl;
            }
        }
        __syncthreads();

#pragma unroll
        for (int ks = 0; ks < 4; ++ks) {
            const int arow = mt * 16 + fr;
            const int aoff = arow * 128 + ((ks * 32 + fh * 8) ^ ((arow & 7) << 3));
            bf16x8 ah = *(const bf16x8*)&XsHi[aoff];
            bf16x8 al = *(const bf16x8*)&XsLo[aoff];
#pragma unroll
            for (int nt = 0; nt < 4; ++nt) {
                const int brow = (ntb + nt) * 16 + fr;
                const int boff = brow * 128 + ((ks * 32 + fh * 8) ^ ((brow & 7) << 3));
                bf16x8 bh = *(const bf16x8*)&WtHi[boff];
                bf16x8 bl = *(const bf16x8*)&WtLo[boff];
                acc[nt] = __builtin_amdgcn_mfma_f32_16x16x32_bf16(ah, bh, acc[nt], 0, 0, 0);
                acc[nt] = __builtin_amdgcn_mfma_f32_16x16x32_bf16(al, bh, acc[nt], 0, 0, 0);
                acc[nt] = __builtin_amdgcn_mfma_f32_16x16x32_bf16(ah, bl, acc[nt], 0, 0, 0);
            }
        }
    }

#pragma unroll
    for (int nt = 0; nt < 4; ++nt) {
        const int col = (ntb + nt) * 16 + fr;
#pragma unroll
        for (int i = 0; i < 4; ++i) {
            const int rr = row0 + mt * 16 + fh * 4 + i;
            if (rr < N) out[(size_t)rr * 128 + col] = acc[nt][i];
        }
    }
}

// ---------------------------------------------------------------------------
// CSR build, two-pass LDS-binned partition. Buckets = 32 consecutive rows.
// No global atomics anywhere; all global writes dense or block-private bursts.
// ---------------------------------------------------------------------------

// P1a (fused with X->bf16 conversion): per-block LDS histogram over buckets.
// blockcounts laid out bucket-major: blockcounts[b*KPART + k].
__global__ void part_count_conv_kernel(const int* __restrict__ erows, int E,
                                       int* __restrict__ blockcounts, int NB, int chunk,
                                       const float* __restrict__ X,
                                       ushort* __restrict__ Xbf, int ngroups, int cb) {
    __shared__ int hist[MAXNB];
    const int b = blockIdx.x;
    const int tid = threadIdx.x;
    if (b < cb) {
        int i = b * 256 + tid;
        if (i < ngroups) {
            const float4* __restrict__ X4 = (const float4*)X;
            float4 v0 = X4[i * 2 + 0];
            float4 v1 = X4[i * 2 + 1];
            u16x8 o;
            o[0] = f2bf(v0.x); o[1] = f2bf(v0.y); o[2] = f2bf(v0.z); o[3] = f2bf(v0.w);
            o[4] = f2bf(v1.x); o[5] = f2bf(v1.y); o[6] = f2bf(v1.z); o[7] = f2bf(v1.w);
            ((u16x8*)Xbf)[i] = o;
        }
        return;
    }
    const int k = b - cb;
    for (int i = tid; i < NB; i += 256) hist[i] = 0;
    __syncthreads();
    const int e0 = k * chunk;
    const int e1 = (e0 + chunk < E) ? e0 + chunk : E;
    for (int i = e0 + tid; i < e1; i += 256)
        atomicAdd(&hist[erows[i] >> 5], 1);
    __syncthreads();
    for (int i = tid; i < NB; i += 256) blockcounts[i * KPART + k] = hist[i];
}

// Pscan1: per-bucket exclusive scan over the KPART block counts (in place),
// emitting bucket totals. One wave per bucket.
__global__ void part_scan1_kernel(int* __restrict__ blockcounts,
                                  int* __restrict__ btotal, int NB) {
    const int tid = threadIdx.x;
    const int lane = tid & 63;
    const int b = blockIdx.x * 4 + (tid >> 6);
    if (b >= NB) return;
    int* __restrict__ row = blockcounts + (size_t)b * KPART;
    int c0 = row[lane * 4 + 0];
    int c1 = row[lane * 4 + 1];
    int c2 = row[lane * 4 + 2];
    int c3 = row[lane * 4 + 3];
    int lsum = c0 + c1 + c2 + c3;
    int s = lsum;
#pragma unroll
    for (int off = 1; off < 64; off <<= 1) {
        int t = __shfl_up(s, off);
        if (lane >= off) s += t;
    }
    int run = s - lsum;  // exclusive prefix of this lane's group
    row[lane * 4 + 0] = run; run += c0;
    row[lane * 4 + 1] = run; run += c1;
    row[lane * 4 + 2] = run; run += c2;
    row[lane * 4 + 3] = run;
    if (lane == 63) btotal[b] = s;
}

// Pscan2: single-block exclusive scan of bucket totals -> bucketBase.
__global__ __launch_bounds__(1024)
void part_scan2_kernel(const int* __restrict__ btotal, int* __restrict__ bbase,
                       int NB, int E, int* __restrict__ rowptr, int N) {
    __shared__ int sums[1024];
    const int tid = threadIdx.x;
    const int items = (NB + 1023) >> 10;  // 2 for NB=1563
    const int start = tid * items;
    const int end = (start + items < NB) ? start + items : NB;
    int s = 0;
    for (int i = start; i < end; ++i) s += btotal[i];
    sums[tid] = s;
    __syncthreads();
#pragma unroll
    for (int off = 1; off < 1024; off <<= 1) {
        int t = (tid >= off) ? sums[tid - off] : 0;
        __syncthreads();
        sums[tid] += t;
        __syncthreads();
    }
    int run = sums[tid] - s;
    for (int i = start; i < end; ++i) {
        bbase[i] = run;
        run += btotal[i];
    }
    if (tid == 0) { bbase[NB] = E; rowptr[N] = E; }
}

// P1b: place edges into bucket-grouped intermediate (payload carried along).
// Entry: .x = (row&31)<<16 | col  (col < 65536), .y = bits(2*val).
__global__ void part_place_kernel(const int* __restrict__ erows,
                                  const int* __restrict__ ecols,
                                  const float* __restrict__ evals, int E,
                                  const int* __restrict__ blockcounts,
                                  const int* __restrict__ bbase, int NB, int chunk,
                                  int2* __restrict__ bucketed) {
    __shared__ int cur[MAXNB];
    const int k = blockIdx.x;
    const int tid = threadIdx.x;
    for (int i = tid; i < NB; i += 256)
        cur[i] = bbase[i] + blockcounts[(size_t)i * KPART + k];
    __syncthreads();
    const int e0 = k * chunk;
    const int e1 = (e0 + chunk < E) ? e0 + chunk : E;
    for (int i = e0 + tid; i < e1; i += 256) {
        int r = erows[i];
        int pos = atomicAdd(&cur[r >> 5], 1);  // LDS atomic
        int2 p;
        p.x = (int)(((uint32_t)(r & 31) << 16) | (uint32_t)ecols[i]);
        p.y = __float_as_int(2.0f * evals[i]);
        bucketed[pos] = p;
    }
}

// P2: one block per bucket. Count 32 rows, scan, emit rowptr + grouped CSR.
__global__ void part_finish_kernel(const int2* __restrict__ bucketed,
                                   const int* __restrict__ bbase,
                                   int* __restrict__ rowptr,
                                   int2* __restrict__ csr, int N) {
    __shared__ int rcnt[32];
    __shared__ int rpos[32];
    const int b = blockIdx.x;
    const int tid = threadIdx.x;
    const int base = bbase[b];
    const int end = bbase[b + 1];
    const int row0 = b * 32;
    if (tid < 32) rcnt[tid] = 0;
    __syncthreads();
    for (int i = base + tid; i < end; i += 256)
        atomicAdd(&rcnt[((uint32_t)bucketed[i].x) >> 16], 1);
    __syncthreads();
    if (tid == 0) {
        int run = base;
        for (int j = 0; j < 32; ++j) {
            int c = rcnt[j];
            rpos[j] = run;
            if (row0 + j < N) rowptr[row0 + j] = run;
            run += c;
        }
    }
    __syncthreads();
    for (int i = base + tid; i < end; i += 256) {
        int2 e = bucketed[i];
        uint32_t meta = (uint32_t)e.x;
        int pos = atomicAdd(&rpos[meta >> 16], 1);  // LDS atomic
        int2 p;
        p.x = (int)(meta & 0xFFFFu);
        p.y = e.y;
        csr[pos] = p;
    }
}

// ---------------------------------------------------------------------------
// Gather SpMM over bf16 source (R8-verified).
// ---------------------------------------------------------------------------
__device__ __forceinline__ float4 bf4f(ushort4 v) {
    float4 r;
    r.x = bf2f(v.x); r.y = bf2f(v.y); r.z = bf2f(v.z); r.w = bf2f(v.w);
    return r;
}

template <bool WRITE_BF>
__global__ __launch_bounds__(256, 8)
void spmm_gather_bf(const int* __restrict__ rowptr, const int2* __restrict__ csr,
                    const ushort* __restrict__ src, const float* __restrict__ init,
                    void* __restrict__ dst, int N) {
    long long idx = (long long)blockIdx.x * blockDim.x + threadIdx.x;
    int row = (int)(idx >> 5);
    if (row >= N) return;
    int lane = (int)(idx & 31);
    const ushort4* __restrict__ S4 = (const ushort4*)src;
    float4 accA = {0.f, 0.f, 0.f, 0.f};
    float4 accB = {0.f, 0.f, 0.f, 0.f};
    if (init) {
        float4 t = ((const float4*)init)[(size_t)row * 32 + lane];
        accA.x = -t.x; accA.y = -t.y; accA.z = -t.z; accA.w = -t.w;
    }
    int p = rowptr[row];
    const int p1 = rowptr[row + 1];
    for (; p + 7 < p1; p += 8) {
        int2 cv0 = csr[p + 0];
        int2 cv1 = csr[p + 1];
        int2 cv2 = csr[p + 2];
        int2 cv3 = csr[p + 3];
        int2 cv4 = csr[p + 4];
        int2 cv5 = csr[p + 5];
        int2 cv6 = csr[p + 6];
        int2 cv7 = csr[p + 7];
        float4 x0 = bf4f(S4[(size_t)cv0.x * 32 + lane]);
        float4 x1 = bf4f(S4[(size_t)cv1.x * 32 + lane]);
        float4 x2 = bf4f(S4[(size_t)cv2.x * 32 + lane]);
        float4 x3 = bf4f(S4[(size_t)cv3.x * 32 + lane]);
        float4 x4 = bf4f(S4[(size_t)cv4.x * 32 + lane]);
        float4 x5 = bf4f(S4[(size_t)cv5.x * 32 + lane]);
        float4 x6 = bf4f(S4[(size_t)cv6.x * 32 + lane]);
        float4 x7 = bf4f(S4[(size_t)cv7.x * 32 + lane]);
        float v0 = __int_as_float(cv0.y);
        float v1 = __int_as_float(cv1.y);
        float v2 = __int_as_float(cv2.y);
        float v3 = __int_as_float(cv3.y);
        float v4 = __int_as_float(cv4.y);
        float v5 = __int_as_float(cv5.y);
        float v6 = __int_as_float(cv6.y);
        float v7 = __int_as_float(cv7.y);
        accA.x = fmaf(v0, x0.x, accA.x); accA.y = fmaf(v0, x0.y, accA.y);
        accA.z = fmaf(v0, x0.z, accA.z); accA.w = fmaf(v0, x0.w, accA.w);
        accB.x = fmaf(v1, x1.x, accB.x); accB.y = fmaf(v1, x1.y, accB.y);
        accB.z = fmaf(v1, x1.z, accB.z); accB.w = fmaf(v1, x1.w, accB.w);
        accA.x = fmaf(v2, x2.x, accA.x); accA.y = fmaf(v2, x2.y, accA.y);
        accA.z = fmaf(v2, x2.z, accA.z); accA.w = fmaf(v2, x2.w, accA.w);
        accB.x = fmaf(v3, x3.x, accB.x); accB.y = fmaf(v3, x3.y, accB.y);
        accB.z = fmaf(v3, x3.z, accB.z); accB.w = fmaf(v3, x3.w, accB.w);
        accA.x = fmaf(v4, x4.x, accA.x); accA.y = fmaf(v4, x4.y, accA.y);
        accA.z = fmaf(v4, x4.z, accA.z); accA.w = fmaf(v4, x4.w, accA.w);
        accB.x = fmaf(v5, x5.x, accB.x); accB.y = fmaf(v5, x5.y, accB.y);
        accB.z = fmaf(v5, x5.z, accB.z); accB.w = fmaf(v5, x5.w, accB.w);
        accA.x = fmaf(v6, x6.x, accA.x); accA.y = fmaf(v6, x6.y, accA.y);
        accA.z = fmaf(v6, x6.z, accA.z); accA.w = fmaf(v6, x6.w, accA.w);
        accB.x = fmaf(v7, x7.x, accB.x); accB.y = fmaf(v7, x7.y, accB.y);
        accB.z = fmaf(v7, x7.z, accB.z); accB.w = fmaf(v7, x7.w, accB.w);
    }
    for (; p + 3 < p1; p += 4) {
        int2 cv0 = csr[p + 0];
        int2 cv1 = csr[p + 1];
        int2 cv2 = csr[p + 2];
        int2 cv3 = csr[p + 3];
        float4 x0 = bf4f(S4[(size_t)cv0.x * 32 + lane]);
        float4 x1 = bf4f(S4[(size_t)cv1.x * 32 + lane]);
        float4 x2 = bf4f(S4[(size_t)cv2.x * 32 + lane]);
        float4 x3 = bf4f(S4[(size_t)cv3.x * 32 + lane]);
        float v0 = __int_as_float(cv0.y);
        float v1 = __int_as_float(cv1.y);
        float v2 = __int_as_float(cv2.y);
        float v3 = __int_as_float(cv3.y);
        accA.x = fmaf(v0, x0.x, accA.x); accA.y = fmaf(v0, x0.y, accA.y);
        accA.z = fmaf(v0, x0.z, accA.z); accA.w = fmaf(v0, x0.w, accA.w);
        accB.x = fmaf(v1, x1.x, accB.x); accB.y = fmaf(v1, x1.y, accB.y);
        accB.z = fmaf(v1, x1.z, accB.z); accB.w = fmaf(v1, x1.w, accB.w);
        accA.x = fmaf(v2, x2.x, accA.x); accA.y = fmaf(v2, x2.y, accA.y);
        accA.z = fmaf(v2, x2.z, accA.z); accA.w = fmaf(v2, x2.w, accA.w);
        accB.x = fmaf(v3, x3.x, accB.x); accB.y = fmaf(v3, x3.y, accB.y);
        accB.z = fmaf(v3, x3.z, accB.z); accB.w = fmaf(v3, x3.w, accB.w);
    }
    for (; p < p1; ++p) {
        int2 cv = csr[p];
        float v = __int_as_float(cv.y);
        float4 x = bf4f(S4[(size_t)cv.x * 32 + lane]);
        accA.x = fmaf(v, x.x, accA.x);
        accA.y = fmaf(v, x.y, accA.y);
        accA.z = fmaf(v, x.z, accA.z);
        accA.w = fmaf(v, x.w, accA.w);
    }
    float4 acc;
    acc.x = accA.x + accB.x;
    acc.y = accA.y + accB.y;
    acc.z = accA.z + accB.z;
    acc.w = accA.w + accB.w;
    if (WRITE_BF) {
        ushort4 o;
        o.x = f2bf(acc.x); o.y = f2bf(acc.y); o.z = f2bf(acc.z); o.w = f2bf(acc.w);
        ((ushort4*)dst)[(size_t)row * 32 + lane] = o;
    } else {
        ((float4*)dst)[(size_t)row * 32 + lane] = acc;
    }
}

extern "C" void kernel_launch(void* const* d_in, const int* in_sizes, int n_in,
                              void* d_out, int out_size, void* d_ws, size_t ws_size,
                              hipStream_t stream) {
    const float* X     = (const float*)d_in[0];
    const int*   erows = (const int*)d_in[1];
    const int*   ecols = (const int*)d_in[2];
    const float* evals = (const float*)d_in[3];
    const float* W     = (const float*)d_in[4];
    float* out = (float*)d_out;

    const int N = in_sizes[0] / 128;  // 50000 (cols fit 16 bits; NB <= MAXNB)
    const int E = in_sizes[1];        // 800000

    // Workspace layout (bases 16B-aligned). bucketed aliases u2: the
    // intermediate dies in part_finish, before spmm2 writes u2.
    ushort* t2bf    = (ushort*)d_ws;                    // N*128 u16
    float*  u2      = (float*)(t2bf + (size_t)N * 128); // N*128 f32
    int2*   bucketed= (int2*)u2;                        // E int2 (alias, 6.4MB<25.6MB)
    ushort* xbf     = (ushort*)(u2 + (size_t)N * 128);  // N*128 u16
    ushort* wtab    = xbf + (size_t)N * 128;            // 65536 u16
    ushort* w3t_hi  = wtab;
    ushort* w3t_lo  = wtab + 16384;
    ushort* nw2t_hi = wtab + 32768;
    ushort* nw2t_lo = wtab + 49152;
    int2*   csr     = (int2*)(wtab + 65536);            // E int2
    int*    rowptr  = (int*)(csr + E);                  // N+1
    int*    blkcnt  = rowptr + (N + 1);                 // NB*KPART
    const int NB    = (N + 31) >> 5;                    // 1563
    int*    btotal  = blkcnt + (size_t)NB * KPART;      // NB
    int*    bbase   = btotal + NB;                      // NB+1

    const int chunk    = (E + KPART - 1) / KPART;       // 3125
    const int ngroups  = N * 16;
    const int cb       = (ngroups + 255) / 256;
    const int g_blocks = (int)(((long long)N * 32 + 255) / 256);
    const int d_blocks = (N + 31) / 32;

    // --- W powers ---
    wpow_kernel<<<8, THREADS, 0, stream>>>(W, w3t_hi, w3t_lo, nw2t_hi, nw2t_lo);

    // --- CSR build: LDS-binned two-pass partition (+ fused X->bf16) ---
    part_count_conv_kernel<<<cb + KPART, THREADS, 0, stream>>>(erows, E, blkcnt, NB,
                                                               chunk, X, xbf, ngroups, cb);
    part_scan1_kernel<<<(NB + 3) / 4, THREADS, 0, stream>>>(blkcnt, btotal, NB);
    part_scan2_kernel<<<1, 1024, 0, stream>>>(btotal, bbase, NB, E, rowptr, N);
    part_place_kernel<<<KPART, THREADS, 0, stream>>>(erows, ecols, evals, E, blkcnt,
                                                     bbase, NB, chunk, bucketed);
    part_finish_kernel<<<NB, THREADS, 0, stream>>>(bucketed, bbase, rowptr, csr, N);

    // --- Chebyshev chain (reassociated) ---
    // t2bf = bf16(2A.Xbf - X)
    spmm_gather_bf<true><<<g_blocks, THREADS, 0, stream>>>(rowptr, csr, xbf, X, t2bf, N);
    // u2 = 2A.t2bf  (f32; overwrites the dead bucketed alias)
    spmm_gather_bf<false><<<g_blocks, THREADS, 0, stream>>>(rowptr, csr, t2bf, nullptr, u2, N);
    // out = u2@W3 - X@W2
    gemm_dual_mfma<<<d_blocks, THREADS, 0, stream>>>(u2, w3t_hi, w3t_lo,
                                                     X, nw2t_hi, nw2t_lo, out, N);
}